// Round 4
// baseline (625.400 us; speedup 1.0000x reference)
//
#include <hip/hip_runtime.h>
#include <hip/hip_bf16.h>
#include <stdint.h>

// GateProj: silu((qx @ dequant(W)^T) * qxscale + bias)
// M=4096 K=4096 N=14336 G=128. W int4 packed 8/int32, low nibble first.
//
// Round 8: kill round-7's 4.4e7 LDS conflicts by switching workspace+LDS to
// k-granule-major tiled layout. Per (blk64, kblk64): [kg 0..7][row 0..63][16B]
// = 8KB = one staging sweep. Staging reads contiguous 8KB; 32x32 frag
// ds_reads become contiguous 512B runs (conflict-free by construction); all
// frag offsets are compile-time immediates. 8-phase skeleton, vmcnt chain,
// 32x32x16 MFMA, epilogue identical to round 7.

#define M_DIM 4096
#define K_DIM 4096
#define N_DIM 14336
#define GSZ   128

typedef __bf16 bf16x8 __attribute__((ext_vector_type(8)));
typedef __bf16 bf16x4 __attribute__((ext_vector_type(4)));
typedef float  f32x4  __attribute__((ext_vector_type(4)));
typedef float  f32x16 __attribute__((ext_vector_type(16)));

#define GLOAD16(g, l) __builtin_amdgcn_global_load_lds( \
    (const __attribute__((address_space(1))) void*)(g), \
    (__attribute__((address_space(3))) void*)(l), 16, 0, 0)

#define WAITVM(N) asm volatile("s_waitcnt vmcnt(" #N ")" ::: "memory")
#define WAITLGKM0() asm volatile("s_waitcnt lgkmcnt(0)" ::: "memory")

// ---------------- prepass kernels (write tiled layout) ----------------
// Tiled addr for element (row, k) of a [R,K] matrix:
//   blk = row>>6, r = row&63, kb = k>>6, kg = (k>>3)&7
//   off_elems = ((blk*64 + kb)*512 + kg*64 + r) * 8 + (k&7)

__global__ __launch_bounds__(256) void convertA_kernel(
    const float* __restrict__ qx, __bf16* __restrict__ out)
{
    const size_t i = ((size_t)blockIdx.x * 256 + threadIdx.x) * 8;
    const int row = (int)(i >> 12);          // K=4096
    const int k   = (int)(i & 4095);
    const float4 a = *(const float4*)(qx + i);
    const float4 b = *(const float4*)(qx + i + 4);
    bf16x8 v;
    v[0] = (__bf16)a.x; v[1] = (__bf16)a.y; v[2] = (__bf16)a.z; v[3] = (__bf16)a.w;
    v[4] = (__bf16)b.x; v[5] = (__bf16)b.y; v[6] = (__bf16)b.z; v[7] = (__bf16)b.w;
    const size_t off = ((((size_t)(row >> 6)) * 64 + (k >> 6)) * 512
                        + (size_t)((k >> 3) & 7) * 64 + (row & 63)) * 8;
    *(bf16x8*)(out + off) = v;
}

__global__ __launch_bounds__(256) void dequantW_kernel(
    const int* __restrict__ wq, const float* __restrict__ wscale,
    __bf16* __restrict__ out)
{
    const size_t g = (size_t)blockIdx.x * 256 + threadIdx.x;  // word index
    const int n  = (int)(g >> 9);                             // 512 words/row
    const int wi = (int)(g & 511);                            // k = wi*8
    const float s = wscale[(size_t)n * (K_DIM / GSZ) + (wi >> 4)];
    const int w = wq[g];
    bf16x8 v;
    #pragma unroll
    for (int j = 0; j < 8; ++j) {
        const int q = ((int)((unsigned)w << (28 - 4 * j))) >> 28;
        v[j] = (__bf16)((float)q * s);
    }
    const size_t off = ((((size_t)(n >> 6)) * 64 + (wi >> 3)) * 512
                        + (size_t)(wi & 7) * 64 + (n & 63)) * 8;
    *(bf16x8*)(out + off) = v;
}

// ---------------- main GEMM: 256^2 8-phase, 32x32x16, k-major LDS ---------

constexpr int BM = 256, BN = 256, BK = 64;
constexpr int NT  = K_DIM / BK;         // 64 K-tiles
constexpr int NIT = NT / 2;             // 32 iterations (2 tiles/iter)
constexpr int BUF_BYTES = 65536;        // A 32KB + B 32KB per K-tile
constexpr size_t TB = 8192;             // bytes per (blk64, kblk64) tile-block

__global__ __launch_bounds__(512, 2) void gemm256_kernel(
    const __bf16* __restrict__ A,       // tiled [M/64][K/64][8][64][8e]
    const __bf16* __restrict__ B,       // tiled [N/64][K/64][8][64][8e]
    const float* __restrict__ qxscale,  // [M]
    const float* __restrict__ bias,     // [N]
    float* __restrict__ out)            // [M,N]
{
    __shared__ __align__(16) char smem[2 * BUF_BYTES];   // 128 KiB

    const int t    = threadIdx.x;
    const int lane = t & 63;
    const int wave = t >> 6;
    const int wr   = wave >> 2;   // 0..1 -> M half (128 rows)
    const int wc   = wave & 3;    // 0..3 -> N quarter (64 cols)

    // XCD-bijective swizzle: nwg=896 (16x56), 896%8==0, m-major within chunk
    const int bid = blockIdx.x;
    const int cpx = (M_DIM / BM) * (N_DIM / BN) / 8;   // 112
    const int wg  = (bid & 7) * cpx + (bid >> 3);
    const int tiles_n = N_DIM / BN;                    // 56
    const int tm = wg / tiles_n, tn = wg % tiles_n;
    const int m0 = tm * BM, n0 = tn * BN;

    const char* aWS = (const char*)A;
    const char* bWS = (const char*)B;
    char* sbase = smem;

    // staging: quarter q of K-tile `tile` = tile-block (blk0+q, tile):
    // contiguous 8KB in workspace -> linear 8KB in LDS. One gload/sweep.
    auto STAGE_AQ = [&](int tile, int q) {
        GLOAD16(aWS + (((size_t)(m0 >> 6) + q) * 64 + tile) * TB + t * 16,
                sbase + (tile & 1) * BUF_BYTES + q * 8192 + t * 16);
    };
    auto STAGE_BQ = [&](int tile, int q) {
        GLOAD16(bWS + (((size_t)(n0 >> 6) + q) * 64 + tile) * TB + t * 16,
                sbase + (tile & 1) * BUF_BYTES + 32768 + q * 8192 + t * 16);
    };

    // --- ds_read (32x32x16 frags), k-major LDS quarter [kg][row][16B]:
    // lane row = lane&31, k-granule = kk*2 + (lane>>5).
    // addr = quarter*8192 + (2kk+h)*1024 + rowlocal*16  -> contiguous 512B
    // runs per half-wave; conflict-free; kk/mi/ni offsets are immediates.
    const int lane31 = lane & 31;
    const int h      = lane >> 5;                      // 0..1
    const int aOff = h * 1024 + lane31 * 16;
    const int bOff = 32768 + wc * 8192 + h * 1024 + lane31 * 16;

    f32x16 acc[4][2] = {};
    bf16x8 af[2][4], bfr[2][4];

    auto DS_A = [&](const char* buf, int mibase) {     // 8 x ds_read_b128
        #pragma unroll
        for (int mi = 0; mi < 2; ++mi) {
            const int ma = mibase + mi;   // abs m index 0..3 (32 rows each)
            const int base = (wr * 2 + (ma >> 1)) * 8192 + (ma & 1) * 512 + aOff;
            #pragma unroll
            for (int kk = 0; kk < 4; ++kk)
                af[mi][kk] = *(const bf16x8*)(buf + base + kk * 2048);
        }
    };
    auto DS_B = [&](const char* buf, int ni) {         // 4 x ds_read_b128
        #pragma unroll
        for (int kk = 0; kk < 4; ++kk)
            bfr[ni][kk] = *(const bf16x8*)(buf + bOff + ni * 512 + kk * 2048);
    };
    auto MQ = [&](int mib, int ni) {                   // 8 x mfma_32x32x16
        #pragma unroll
        for (int kk = 0; kk < 4; ++kk)
            #pragma unroll
            for (int mi = 0; mi < 2; ++mi)
                acc[mib + mi][ni] = __builtin_amdgcn_mfma_f32_32x32x16_bf16(
                    af[mi][kk], bfr[ni][kk], acc[mib + mi][ni], 0, 0, 0);
    };

    #define PH_SYNC() do { __builtin_amdgcn_s_barrier(); WAITLGKM0(); \
        __builtin_amdgcn_sched_barrier(0); __builtin_amdgcn_s_setprio(1); } while (0)
    #define PH_END() do { __builtin_amdgcn_s_setprio(0); \
        __builtin_amdgcn_s_barrier(); } while (0)

    // --- prologue: tile0 fully (8 sweeps), tile1 Aq0,Aq2,Bq0-3 (6 sweeps).
    #pragma unroll
    for (int q = 0; q < 4; ++q) STAGE_AQ(0, q);
    #pragma unroll
    for (int q = 0; q < 4; ++q) STAGE_BQ(0, q);
    STAGE_AQ(1, 0); STAGE_AQ(1, 2);
    #pragma unroll
    for (int q = 0; q < 4; ++q) STAGE_BQ(1, q);
    WAITVM(6);
    __builtin_amdgcn_s_barrier();
    __builtin_amdgcn_sched_barrier(0);

    for (int i = 0; i < NIT; ++i) {
        const int t0 = 2 * i, t1 = 2 * i + 1;
        const bool more = (i + 1 < NIT);
        const char* bufE = sbase;               // even tile t0
        const char* bufO = sbase + BUF_BYTES;   // odd tile t1

        // ===== tile t0 (bufE) =====
        // ph1: reads af(m0,1) + bf0 (12); stage t1's A q1,q3
        DS_A(bufE, 0); DS_B(bufE, 0);
        STAGE_AQ(t1, 1); STAGE_AQ(t1, 3);
        PH_SYNC(); MQ(0, 0); PH_END();

        // ph2: reads bf1 (4); stage (t0+2) A q0,q2
        DS_B(bufE, 1);
        if (more) { STAGE_AQ(t0 + 2, 0); STAGE_AQ(t0 + 2, 2); }
        PH_SYNC(); MQ(0, 1); PH_END();

        // ph3: reads af(m2,3) (8); stage (t0+2) B q0,q1
        DS_A(bufE, 2);
        if (more) { STAGE_BQ(t0 + 2, 0); STAGE_BQ(t0 + 2, 1); }
        PH_SYNC(); MQ(2, 1); PH_END();

        // ph4: no reads; stage (t0+2) B q2,q3; vmcnt -> tile t1 resident
        if (more) { STAGE_BQ(t0 + 2, 2); STAGE_BQ(t0 + 2, 3); WAITVM(6); }
        else      { WAITVM(0); }
        __builtin_amdgcn_s_barrier();
        __builtin_amdgcn_sched_barrier(0);
        __builtin_amdgcn_s_setprio(1);
        MQ(2, 0);
        PH_END();

        // ===== tile t1 (bufO) =====
        // ph5: reads af(m0,1) + bf0; stage (t0+2) A q1,q3
        DS_A(bufO, 0); DS_B(bufO, 0);
        if (more) { STAGE_AQ(t0 + 2, 1); STAGE_AQ(t0 + 2, 3); }
        PH_SYNC(); MQ(0, 0); PH_END();

        // ph6: reads bf1; stage (t1+2) A q0,q2
        DS_B(bufO, 1);
        if (more) { STAGE_AQ(t1 + 2, 0); STAGE_AQ(t1 + 2, 2); }
        PH_SYNC(); MQ(0, 1); PH_END();

        // ph7: reads af(m2,3); stage (t1+2) B q0,q1
        DS_A(bufO, 2);
        if (more) { STAGE_BQ(t1 + 2, 0); STAGE_BQ(t1 + 2, 1); }
        PH_SYNC(); MQ(2, 1); PH_END();

        // ph8: no reads; stage (t1+2) B q2,q3; vmcnt -> tile t0+2 resident
        if (more) { STAGE_BQ(t1 + 2, 2); STAGE_BQ(t1 + 2, 3); WAITVM(6); }
        __builtin_amdgcn_s_barrier();
        __builtin_amdgcn_sched_barrier(0);
        __builtin_amdgcn_s_setprio(1);
        MQ(2, 0);
        PH_END();
    }

    #undef PH_SYNC
    #undef PH_END

    // ---- epilogue: y = acc*qxscale[m] + bias[n]; silu ----
    // D (32x32): col = lane&31 (n), row = (reg&3) + 8*(reg>>2) + 4*h (m)
    const int c_col = lane31;
    const int hh4   = h * 4;
    float bv[2];
    #pragma unroll
    for (int ni = 0; ni < 2; ++ni)
        bv[ni] = bias[n0 + wc * 64 + ni * 32 + c_col];
    #pragma unroll
    for (int mi = 0; mi < 4; ++mi) {
        #pragma unroll
        for (int rq = 0; rq < 4; ++rq) {
            const int mg = m0 + wr * 128 + mi * 32 + rq * 8 + hh4;
            float qs[4];
            #pragma unroll
            for (int r = 0; r < 4; ++r) qs[r] = qxscale[mg + r];
            #pragma unroll
            for (int ni = 0; ni < 2; ++ni) {
                const int ng = n0 + wc * 64 + ni * 32 + c_col;
                #pragma unroll
                for (int r = 0; r < 4; ++r) {
                    const float y = acc[mi][ni][rq * 4 + r] * qs[r] + bv[ni];
                    out[(size_t)(mg + r) * N_DIM + ng] = y / (1.f + __expf(-y));
                }
            }
        }
    }
}

// ---------------- fallback: round-1 fused kernel ----------------

constexpr int FBM = 128, FBN = 128, FBK = 64;
constexpr int FLDA = 72;

__global__ __launch_bounds__(256) void gateproj_fused_kernel(
    const float* __restrict__ qx, const float* __restrict__ qxscale,
    const int* __restrict__ wq, const float* __restrict__ wscale,
    const float* __restrict__ bias, float* __restrict__ out)
{
    __shared__ __bf16 sA[FBM * FLDA];
    __shared__ __bf16 sB[FBN * FLDA];

    const int tid  = threadIdx.x;
    const int lane = tid & 63;
    const int wave = tid >> 6;
    const int wm = wave >> 1, wn = wave & 1;

    const int bid = blockIdx.x;
    const int cpx = (M_DIM / FBM) * (N_DIM / FBN) / 8;
    const int wg  = (bid & 7) * cpx + (bid >> 3);
    const int tiles_n = N_DIM / FBN;
    const int tm = wg / tiles_n, tn = wg % tiles_n;
    const int m0 = tm * FBM, n0 = tn * FBN;

    const int a_row = tid >> 4;
    const int a_col = (tid & 15) * 4;
    const float* aPtr = qx + (size_t)(m0 + a_row) * K_DIM + a_col;

    const int b_row = tid >> 1;
    const int b_wb  = (tid & 1) * 4;
    const int*   bPtr = wq     + (size_t)(n0 + b_row) * (K_DIM / 8) + b_wb;
    const float* sPtr = wscale + (size_t)(n0 + b_row) * (K_DIM / GSZ);

    float4 aReg[8];
    int    bRegW[4];
    float  bScl;
    f32x4 acc[4][4] = {};

    auto LOAD = [&](int kt) {
        const float* ap = aPtr + kt * FBK;
        #pragma unroll
        for (int i = 0; i < 8; ++i)
            aReg[i] = *(const float4*)(ap + (size_t)i * 16 * K_DIM);
        int4 b = *(const int4*)(bPtr + kt * 8);
        bRegW[0] = b.x; bRegW[1] = b.y; bRegW[2] = b.z; bRegW[3] = b.w;
        bScl = sPtr[kt >> 1];
    };

    auto STORE = [&]() {
        #pragma unroll
        for (int i = 0; i < 8; ++i) {
            bf16x4 v;
            v[0] = (__bf16)aReg[i].x; v[1] = (__bf16)aReg[i].y;
            v[2] = (__bf16)aReg[i].z; v[3] = (__bf16)aReg[i].w;
            *(bf16x4*)&sA[(a_row + i * 16) * FLDA + a_col] = v;
        }
        const int cb = (tid & 1) * 32;
        #pragma unroll
        for (int wi = 0; wi < 4; ++wi) {
            const int w = bRegW[wi];
            bf16x8 o;
            #pragma unroll
            for (int j = 0; j < 8; ++j) {
                const int v = ((int)((unsigned)w << (28 - 4 * j))) >> 28;
                o[j] = (__bf16)((float)v * bScl);
            }
            *(bf16x8*)&sB[b_row * FLDA + cb + wi * 8] = o;
        }
    };

    LOAD(0); STORE(); __syncthreads();

    const int FNT = K_DIM / FBK;
    for (int kt = 0; kt < FNT; ++kt) {
        if (kt + 1 < FNT) LOAD(kt + 1);
        #pragma unroll
        for (int kk = 0; kk < 2; ++kk) {
            bf16x8 af2[4], bfr2[4];
            const int ko = kk * 32 + (lane >> 4) * 8;
            #pragma unroll
            for (int mi = 0; mi < 4; ++mi)
                af2[mi] = *(const bf16x8*)&sA[(wm * 64 + mi * 16 + (lane & 15)) * FLDA + ko];
            #pragma unroll
            for (int ni = 0; ni < 4; ++ni)
                bfr2[ni] = *(const bf16x8*)&sB[(wn * 64 + ni * 16 + (lane & 15)) * FLDA + ko];
            #pragma unroll
            for (int mi = 0; mi < 4; ++mi)
                #pragma unroll
                for (int ni = 0; ni < 4; ++ni)
                    acc[mi][ni] = __builtin_amdgcn_mfma_f32_16x16x32_bf16(
                        af2[mi], bfr2[ni], acc[mi][ni], 0, 0, 0);
        }
        __syncthreads();
        if (kt + 1 < FNT) { STORE(); __syncthreads(); }
    }

    const int c_col = lane & 15;
    const int c_r4  = (lane >> 4) * 4;
    #pragma unroll
    for (int mi = 0; mi < 4; ++mi) {
        const int mg = m0 + wm * 64 + mi * 16 + c_r4;
        float qs[4];
        #pragma unroll
        for (int r = 0; r < 4; ++r) qs[r] = qxscale[mg + r];
        #pragma unroll
        for (int ni = 0; ni < 4; ++ni) {
            const int ng = n0 + wn * 64 + ni * 16 + c_col;
            const float bv = bias[ng];
            #pragma unroll
            for (int r = 0; r < 4; ++r) {
                const float y = acc[mi][ni][r] * qs[r] + bv;
                out[(size_t)(mg + r) * N_DIM + ng] = y / (1.f + __expf(-y));
            }
        }
    }
}

// ---------------- launch ----------------

extern "C" void kernel_launch(void* const* d_in, const int* in_sizes, int n_in,
                              void* d_out, int out_size, void* d_ws, size_t ws_size,
                              hipStream_t stream) {
    const float* qx      = (const float*)d_in[0];
    const float* qxscale = (const float*)d_in[1];
    const int*   wq      = (const int*)d_in[2];
    const float* wscale  = (const float*)d_in[3];
    const float* bias    = (const float*)d_in[4];
    float* out = (float*)d_out;

    const size_t needA = (size_t)M_DIM * K_DIM * 2;
    const size_t needW = (size_t)N_DIM * K_DIM * 2;

    if (ws_size >= needA + needW) {
        __bf16* Abf = (__bf16*)d_ws;
        __bf16* Wbf = Abf + (size_t)M_DIM * K_DIM;

        hipLaunchKernelGGL(convertA_kernel, dim3(M_DIM * K_DIM / 8 / 256), dim3(256),
                           0, stream, qx, Abf);
        hipLaunchKernelGGL(dequantW_kernel, dim3(N_DIM * (K_DIM / 8) / 256), dim3(256),
                           0, stream, wq, wscale, Wbf);

        const int grid = (M_DIM / BM) * (N_DIM / BN);   // 896
        hipLaunchKernelGGL(gemm256_kernel, dim3(grid), dim3(512), 0, stream,
                           Abf, Wbf, qxscale, bias, out);
    } else {
        const int grid = (M_DIM / FBM) * (N_DIM / FBN);
        hipLaunchKernelGGL(gateproj_fused_kernel, dim3(grid), dim3(256), 0, stream,
                           qx, qxscale, wq, wscale, bias, out);
    }
}

// Round 5
// 619.896 us; speedup vs baseline: 1.0089x; 1.0089x over previous
//
#include <hip/hip_runtime.h>
#include <hip/hip_bf16.h>
#include <stdint.h>

// GateProj: silu((qx @ dequant(W)^T) * qxscale + bias)
// M=4096 K=4096 N=14336 G=128. W int4 packed 8/int32, low nibble first.
//
// Round 9: (a) revert to row-major workspace + cheap coalesced prepass
// (round-8 tiled prepass cost ~90us in scattered writes); (b) kill the grid
// tail: tile 128x256 -> 1792 blocks = 7.0 exact block-waves (was 896=3.5,
// last wave half-idle); (c) lighter sync: 4 phases/iter, each
// {16 ds_reads | 6 stage-sweeps, 16 MFMA, counted vmcnt, 1 barrier} ->
// 2 barriers + 1 lgkm per K-tile (was 8 + 2). 16x16x32 MFMA, round-6 XOR
// swizzle (measured 0 conflicts). vmcnt(6) retires exactly one 6-sweep tile.

#define M_DIM 4096
#define K_DIM 4096
#define N_DIM 14336
#define GSZ   128

typedef __bf16 bf16x8 __attribute__((ext_vector_type(8)));
typedef __bf16 bf16x4 __attribute__((ext_vector_type(4)));
typedef float  f32x4  __attribute__((ext_vector_type(4)));

#define GLOAD16(g, l) __builtin_amdgcn_global_load_lds( \
    (const __attribute__((address_space(1))) void*)(g), \
    (__attribute__((address_space(3))) void*)(l), 16, 0, 0)

#define WAITVM(N) asm volatile("s_waitcnt vmcnt(" #N ")" ::: "memory")
#define WAITLGKM(N) asm volatile("s_waitcnt lgkmcnt(" #N ")" ::: "memory")

// ---------------- prepass kernels (row-major bf16 workspace) --------------

__global__ __launch_bounds__(256) void convertA_kernel(
    const float* __restrict__ qx, __bf16* __restrict__ out)
{
    const size_t i = ((size_t)blockIdx.x * 256 + threadIdx.x) * 8;
    const float4 a = *(const float4*)(qx + i);
    const float4 b = *(const float4*)(qx + i + 4);
    bf16x8 v;
    v[0] = (__bf16)a.x; v[1] = (__bf16)a.y; v[2] = (__bf16)a.z; v[3] = (__bf16)a.w;
    v[4] = (__bf16)b.x; v[5] = (__bf16)b.y; v[6] = (__bf16)b.z; v[7] = (__bf16)b.w;
    *(bf16x8*)(out + i) = v;
}

__global__ __launch_bounds__(256) void dequantW_kernel(
    const int* __restrict__ wq, const float* __restrict__ wscale,
    __bf16* __restrict__ out)
{
    const size_t g = (size_t)blockIdx.x * 256 + threadIdx.x;  // word index
    const int n  = (int)(g >> 9);                             // 512 words/row
    const int wi = (int)(g & 511);
    const float s = wscale[(size_t)n * (K_DIM / GSZ) + (wi >> 4)];
    const int w = wq[g];
    bf16x8 v;
    #pragma unroll
    for (int j = 0; j < 8; ++j) {
        const int q = ((int)((unsigned)w << (28 - 4 * j))) >> 28;
        v[j] = (__bf16)((float)q * s);
    }
    *(bf16x8*)(out + g * 8) = v;
}

// ---------------- main GEMM: 128x256, 4-phase light-sync pipeline ---------

constexpr int BM = 128, BN = 256, BK = 64;
constexpr int NT  = K_DIM / BK;         // 64 K-tiles
constexpr int NIT = NT / 2;             // 32 iterations (2 tiles/iter)
constexpr int BUF_BYTES = 49152;        // A 16KB + B 32KB per K-tile

__global__ __launch_bounds__(512, 2) void gemm128_kernel(
    const __bf16* __restrict__ A,       // [M,K] bf16
    const __bf16* __restrict__ B,       // [N,K] bf16
    const float* __restrict__ qxscale,  // [M]
    const float* __restrict__ bias,     // [N]
    float* __restrict__ out)            // [M,N]
{
    __shared__ __align__(16) char smem[2 * BUF_BYTES];   // 96 KiB

    const int t    = threadIdx.x;
    const int lane = t & 63;
    const int wave = t >> 6;
    const int wr   = wave >> 2;   // 0..1 -> M half (64 rows)
    const int wc   = wave & 3;    // 0..3 -> N quarter (64 cols)

    // XCD-bijective swizzle: nwg=1792 (32x56), 1792%8==0, m-major in chunk
    const int bid = blockIdx.x;
    const int cpx = (M_DIM / BM) * (N_DIM / BN) / 8;   // 224
    const int wg  = (bid & 7) * cpx + (bid >> 3);
    const int tiles_n = N_DIM / BN;                    // 56
    const int tm = wg / tiles_n, tn = wg % tiles_n;
    const int m0 = tm * BM, n0 = tn * BN;

    // --- staging: one sweep = 512 thr x 16B = 8KB = 64 rows x 128B.
    // Thread t: row srow=t>>3, phys granule t&7; LDS dest linear; global
    // source granule = (t&7) ^ (srow&7) (involution; rule 21).
    const int srow = t >> 3;
    const int sg16 = (((t & 7) ^ (srow & 7)) << 4);
    const size_t KB = (size_t)K_DIM * 2;               // 8192 bytes/row
    const char* aS = (const char*)A + (size_t)(m0 + srow) * KB + sg16;
    const char* bS = (const char*)B + (size_t)(n0 + srow) * KB + sg16;
    char* sbase = smem;

    auto STAGE_A = [&](int tile, int q) {              // q = 0..1
        GLOAD16(aS + (size_t)tile * 128 + (size_t)q * 64 * KB,
                sbase + (tile & 1) * BUF_BYTES + q * 8192 + t * 16);
    };
    auto STAGE_B = [&](int tile, int q) {              // q = 0..3
        GLOAD16(bS + (size_t)tile * 128 + (size_t)q * 64 * KB,
                sbase + (tile & 1) * BUF_BYTES + 16384 + q * 8192 + t * 16);
    };
    auto STAGE_ALL = [&](int tile) {                   // S(t): 6 sweeps
        STAGE_A(tile, 0); STAGE_A(tile, 1);
        STAGE_B(tile, 0); STAGE_B(tile, 1);
        STAGE_B(tile, 2); STAGE_B(tile, 3);
    };

    // --- ds_read: row = base + lane15 (base%8==0), logical granule
    // g = kk*4 + (lane>>4); phys byte col = ((g ^ (row&7)) << 4).
    // addr(kk=1) = addr(kk=0) ^ 64. Round-6 scheme: measured 0 conflicts.
    const int lane15 = lane & 15;
    const int lc     = lane >> 4;                      // 0..3
    const int swzc   = ((lc ^ (lane15 & 7)) << 4);
    const int aR0 = (wr * 64 + lane15) * 128 + swzc;           // + mi*2048
    const int bR0 = 16384 + (wc * 64 + lane15) * 128 + swzc;   // + ni*2048

    f32x4 acc[4][4] = {};
    bf16x8 af[4][2], bfr[4][2];

    auto DS_TILE = [&](const char* buf) {              // 16 x ds_read_b128
        #pragma unroll
        for (int mi = 0; mi < 4; ++mi) {
            const int a0 = aR0 + mi * 2048;
            af[mi][0] = *(const bf16x8*)(buf + a0);
            af[mi][1] = *(const bf16x8*)(buf + (a0 ^ 64));
        }
        #pragma unroll
        for (int ni = 0; ni < 4; ++ni) {
            const int b0 = bR0 + ni * 2048;
            bfr[ni][0] = *(const bf16x8*)(buf + b0);
            bfr[ni][1] = *(const bf16x8*)(buf + (b0 ^ 64));
        }
    };
    auto MFMA_HALF = [&](int nb) {                     // 16 x mfma 16x16x32
        #pragma unroll
        for (int kk = 0; kk < 2; ++kk)
            #pragma unroll
            for (int mi = 0; mi < 4; ++mi)
                #pragma unroll
                for (int ni = 0; ni < 2; ++ni)
                    acc[mi][nb + ni] = __builtin_amdgcn_mfma_f32_16x16x32_bf16(
                        af[mi][kk], bfr[nb + ni][kk], acc[mi][nb + ni], 0, 0, 0);
    };

    // --- prologue: stage tiles 0 and 1 (12 sweeps); retire S(0).
    STAGE_ALL(0); STAGE_ALL(1);
    WAITVM(6);
    __builtin_amdgcn_s_barrier();
    __builtin_amdgcn_sched_barrier(0);

    for (int i = 0; i < NIT; ++i) {
        const int t0 = 2 * i, t1 = 2 * i + 1;
        const bool more = (i + 1 < NIT);
        const char* bufE = sbase;               // even tile t0
        const char* bufO = sbase + BUF_BYTES;   // odd tile t1

        // ph1: read tile t0 (16), MFMA n-lo. lgkm(4): first 12 reads
        // (A + B-lo) cover this cluster; B-hi rides into ph2 (compiler's
        // own precise waits backstop correctness).
        DS_TILE(bufE);
        WAITLGKM(4);
        __builtin_amdgcn_sched_barrier(0);
        __builtin_amdgcn_s_setprio(1);
        MFMA_HALF(0);
        __builtin_amdgcn_s_setprio(0);
        __builtin_amdgcn_s_barrier();   // seals t0 reads -> ph2 may restage bufE

        // ph2: stage S(t0+2) into bufE; MFMA n-hi (regs); vmcnt(6) retires
        // S(t1) (issued prev ph4) -> barrier publishes t1 residency.
        if (more) STAGE_ALL(t0 + 2);
        __builtin_amdgcn_s_setprio(1);
        MFMA_HALF(2);
        __builtin_amdgcn_s_setprio(0);
        if (more) WAITVM(6); else WAITVM(0);
        __builtin_amdgcn_s_barrier();
        __builtin_amdgcn_sched_barrier(0);

        // ph3: read tile t1, MFMA n-lo
        DS_TILE(bufO);
        WAITLGKM(4);
        __builtin_amdgcn_sched_barrier(0);
        __builtin_amdgcn_s_setprio(1);
        MFMA_HALF(0);
        __builtin_amdgcn_s_setprio(0);
        __builtin_amdgcn_s_barrier();   // seals t1 reads -> ph4 may restage bufO

        // ph4: stage S(t1+2) into bufO; MFMA n-hi; vmcnt(6) retires S(t0+2)
        if (more) STAGE_ALL(t1 + 2);
        __builtin_amdgcn_s_setprio(1);
        MFMA_HALF(2);
        __builtin_amdgcn_s_setprio(0);
        if (more) {
            WAITVM(6);
            __builtin_amdgcn_s_barrier();
            __builtin_amdgcn_sched_barrier(0);
        }
    }

    // ---- epilogue: y = acc*qxscale[m] + bias[n]; silu ----
    // D layout (16x16): col = lane&15 (n), row = (lane>>4)*4 + reg (m)
    const int c_col = lane & 15;
    const int c_r4  = (lane >> 4) * 4;
    #pragma unroll
    for (int mi = 0; mi < 4; ++mi) {
        const int mg = m0 + wr * 64 + mi * 16 + c_r4;
        float qs[4];
        #pragma unroll
        for (int r = 0; r < 4; ++r) qs[r] = qxscale[mg + r];
        #pragma unroll
        for (int ni = 0; ni < 4; ++ni) {
            const int ng = n0 + wc * 64 + ni * 16 + c_col;
            const float bv = bias[ng];
            #pragma unroll
            for (int r = 0; r < 4; ++r) {
                const float y = acc[mi][ni][r] * qs[r] + bv;
                out[(size_t)(mg + r) * N_DIM + ng] = y / (1.f + __expf(-y));
            }
        }
    }
}

// ---------------- fallback: round-1 fused kernel ----------------

constexpr int FBM = 128, FBN = 128, FBK = 64;
constexpr int FLDA = 72;

__global__ __launch_bounds__(256) void gateproj_fused_kernel(
    const float* __restrict__ qx, const float* __restrict__ qxscale,
    const int* __restrict__ wq, const float* __restrict__ wscale,
    const float* __restrict__ bias, float* __restrict__ out)
{
    __shared__ __bf16 sA[FBM * FLDA];
    __shared__ __bf16 sB[FBN * FLDA];

    const int tid  = threadIdx.x;
    const int lane = tid & 63;
    const int wave = tid >> 6;
    const int wm = wave >> 1, wn = wave & 1;

    const int bid = blockIdx.x;
    const int cpx = (M_DIM / FBM) * (N_DIM / FBN) / 8;
    const int wg  = (bid & 7) * cpx + (bid >> 3);
    const int tiles_n = N_DIM / FBN;
    const int tm = wg / tiles_n, tn = wg % tiles_n;
    const int m0 = tm * FBM, n0 = tn * FBN;

    const int a_row = tid >> 4;
    const int a_col = (tid & 15) * 4;
    const float* aPtr = qx + (size_t)(m0 + a_row) * K_DIM + a_col;

    const int b_row = tid >> 1;
    const int b_wb  = (tid & 1) * 4;
    const int*   bPtr = wq     + (size_t)(n0 + b_row) * (K_DIM / 8) + b_wb;
    const float* sPtr = wscale + (size_t)(n0 + b_row) * (K_DIM / GSZ);

    float4 aReg[8];
    int    bRegW[4];
    float  bScl;
    f32x4 acc[4][4] = {};

    auto LOAD = [&](int kt) {
        const float* ap = aPtr + kt * FBK;
        #pragma unroll
        for (int i = 0; i < 8; ++i)
            aReg[i] = *(const float4*)(ap + (size_t)i * 16 * K_DIM);
        int4 b = *(const int4*)(bPtr + kt * 8);
        bRegW[0] = b.x; bRegW[1] = b.y; bRegW[2] = b.z; bRegW[3] = b.w;
        bScl = sPtr[kt >> 1];
    };

    auto STORE = [&]() {
        #pragma unroll
        for (int i = 0; i < 8; ++i) {
            bf16x4 v;
            v[0] = (__bf16)aReg[i].x; v[1] = (__bf16)aReg[i].y;
            v[2] = (__bf16)aReg[i].z; v[3] = (__bf16)aReg[i].w;
            *(bf16x4*)&sA[(a_row + i * 16) * FLDA + a_col] = v;
        }
        const int cb = (tid & 1) * 32;
        #pragma unroll
        for (int wi = 0; wi < 4; ++wi) {
            const int w = bRegW[wi];
            bf16x8 o;
            #pragma unroll
            for (int j = 0; j < 8; ++j) {
                const int v = ((int)((unsigned)w << (28 - 4 * j))) >> 28;
                o[j] = (__bf16)((float)v * bScl);
            }
            *(bf16x8*)&sB[b_row * FLDA + cb + wi * 8] = o;
        }
    };

    LOAD(0); STORE(); __syncthreads();

    const int FNT = K_DIM / FBK;
    for (int kt = 0; kt < FNT; ++kt) {
        if (kt + 1 < FNT) LOAD(kt + 1);
        #pragma unroll
        for (int kk = 0; kk < 2; ++kk) {
            bf16x8 af2[4], bfr2[4];
            const int ko = kk * 32 + (lane >> 4) * 8;
            #pragma unroll
            for (int mi = 0; mi < 4; ++mi)
                af2[mi] = *(const bf16x8*)&sA[(wm * 64 + mi * 16 + (lane & 15)) * FLDA + ko];
            #pragma unroll
            for (int ni = 0; ni < 4; ++ni)
                bfr2[ni] = *(const bf16x8*)&sB[(wn * 64 + ni * 16 + (lane & 15)) * FLDA + ko];
            #pragma unroll
            for (int mi = 0; mi < 4; ++mi)
                #pragma unroll
                for (int ni = 0; ni < 4; ++ni)
                    acc[mi][ni] = __builtin_amdgcn_mfma_f32_16x16x32_bf16(
                        af2[mi], bfr2[ni], acc[mi][ni], 0, 0, 0);
        }
        __syncthreads();
        if (kt + 1 < FNT) { STORE(); __syncthreads(); }
    }

    const int c_col = lane & 15;
    const int c_r4  = (lane >> 4) * 4;
    #pragma unroll
    for (int mi = 0; mi < 4; ++mi) {
        const int mg = m0 + wm * 64 + mi * 16 + c_r4;
        float qs[4];
        #pragma unroll
        for (int r = 0; r < 4; ++r) qs[r] = qxscale[mg + r];
        #pragma unroll
        for (int ni = 0; ni < 4; ++ni) {
            const int ng = n0 + wn * 64 + ni * 16 + c_col;
            const float bv = bias[ng];
            #pragma unroll
            for (int r = 0; r < 4; ++r) {
                const float y = acc[mi][ni][r] * qs[r] + bv;
                out[(size_t)(mg + r) * N_DIM + ng] = y / (1.f + __expf(-y));
            }
        }
    }
}

// ---------------- launch ----------------

extern "C" void kernel_launch(void* const* d_in, const int* in_sizes, int n_in,
                              void* d_out, int out_size, void* d_ws, size_t ws_size,
                              hipStream_t stream) {
    const float* qx      = (const float*)d_in[0];
    const float* qxscale = (const float*)d_in[1];
    const int*   wq      = (const int*)d_in[2];
    const float* wscale  = (const float*)d_in[3];
    const float* bias    = (const float*)d_in[4];
    float* out = (float*)d_out;

    const size_t needA = (size_t)M_DIM * K_DIM * 2;
    const size_t needW = (size_t)N_DIM * K_DIM * 2;

    if (ws_size >= needA + needW) {
        __bf16* Abf = (__bf16*)d_ws;
        __bf16* Wbf = Abf + (size_t)M_DIM * K_DIM;

        hipLaunchKernelGGL(convertA_kernel, dim3(M_DIM * K_DIM / 8 / 256), dim3(256),
                           0, stream, qx, Abf);
        hipLaunchKernelGGL(dequantW_kernel, dim3(N_DIM * (K_DIM / 8) / 256), dim3(256),
                           0, stream, wq, wscale, Wbf);

        const int grid = (M_DIM / BM) * (N_DIM / BN);   // 1792
        hipLaunchKernelGGL(gemm128_kernel, dim3(grid), dim3(512), 0, stream,
                           Abf, Wbf, qxscale, bias, out);
    } else {
        const int grid = (M_DIM / FBM) * (N_DIM / FBN);
        hipLaunchKernelGGL(gateproj_fused_kernel, dim3(grid), dim3(256), 0, stream,
                           qx, qxscale, wq, wscale, bias, out);
    }
}

// Round 6
// 510.512 us; speedup vs baseline: 1.2250x; 1.2143x over previous
//
#include <hip/hip_runtime.h>
#include <hip/hip_bf16.h>
#include <stdint.h>

// GateProj: silu((qx @ dequant(W)^T) * qxscale + bias)
// M=4096 K=4096 N=14336 G=128. W int4 packed 8/int32, low nibble first.
//
// Round 10: fragment-level software pipeline on the round-4 skeleton
// (BM=BN=256, BK=32, 4-deep LDS ring, proven 0-conflict swizzle).
// Per K-tile: {issue c1 reads -> lgkmcnt(4) -> MFMA c0 -> issue next tile's
// c0 reads (alternate reg set) -> lgkmcnt(8) -> MFMA c1 -> vmcnt(4) ->
// barrier}. Reads for the next cluster are always in flight UNDER the
// current MFMA cluster (LDS port ∥ matrix pipe — the round4..9 model shows
// they serialized, summing to the 510us wall). Explicitly double-named frag
// sets (afc/bfc vs afn/bfn) — no runtime indexing.

#define M_DIM 4096
#define K_DIM 4096
#define N_DIM 14336
#define GSZ   128

typedef __bf16 bf16x8 __attribute__((ext_vector_type(8)));
typedef __bf16 bf16x4 __attribute__((ext_vector_type(4)));
typedef float  f32x4  __attribute__((ext_vector_type(4)));

#define GLOAD16(g, l) __builtin_amdgcn_global_load_lds( \
    (const __attribute__((address_space(1))) void*)(g), \
    (__attribute__((address_space(3))) void*)(l), 16, 0, 0)

#define WAITVM(N) asm volatile("s_waitcnt vmcnt(" #N ")" ::: "memory")
#define WAITLGKM(N) asm volatile("s_waitcnt lgkmcnt(" #N ")" ::: "memory")
#define SB0() __builtin_amdgcn_sched_barrier(0)

// ---------------- prepass kernels ----------------

__global__ __launch_bounds__(256) void convertA_kernel(
    const float* __restrict__ qx, __bf16* __restrict__ out)
{
    const size_t i = ((size_t)blockIdx.x * 256 + threadIdx.x) * 8;
    const float4 a = *(const float4*)(qx + i);
    const float4 b = *(const float4*)(qx + i + 4);
    bf16x8 v;
    v[0] = (__bf16)a.x; v[1] = (__bf16)a.y; v[2] = (__bf16)a.z; v[3] = (__bf16)a.w;
    v[4] = (__bf16)b.x; v[5] = (__bf16)b.y; v[6] = (__bf16)b.z; v[7] = (__bf16)b.w;
    *(bf16x8*)(out + i) = v;
}

__global__ __launch_bounds__(256) void dequantW_kernel(
    const int* __restrict__ wq, const float* __restrict__ wscale,
    __bf16* __restrict__ out)
{
    const size_t g = (size_t)blockIdx.x * 256 + threadIdx.x;  // word index
    const int n  = (int)(g >> 9);                             // 512 words/row
    const int wi = (int)(g & 511);
    const float s = wscale[(size_t)n * (K_DIM / GSZ) + (wi >> 4)];
    const int w = wq[g];
    bf16x8 v;
    #pragma unroll
    for (int j = 0; j < 8; ++j) {
        const int q = ((int)((unsigned)w << (28 - 4 * j))) >> 28;
        v[j] = (__bf16)((float)q * s);
    }
    *(bf16x8*)(out + g * 8) = v;
}

// ---------------- main GEMM: 256^2 chunk-pipelined counted-lgkm ----------

constexpr int BM = 256, BN = 256, BK = 32;
constexpr int NT = K_DIM / BK;          // 128
constexpr int BUF_BYTES = 32768;        // A 16KB + B 16KB per K-tile

__global__ __launch_bounds__(512, 2) void gemm256_kernel(
    const __bf16* __restrict__ A,       // [M,K] bf16
    const __bf16* __restrict__ B,       // [N,K] bf16
    const float* __restrict__ qxscale,  // [M]
    const float* __restrict__ bias,     // [N]
    float* __restrict__ out)            // [M,N]
{
    __shared__ __align__(16) char smem[4 * BUF_BYTES];   // 128 KiB, 4-deep

    const int t    = threadIdx.x;
    const int lane = t & 63;
    const int wave = t >> 6;
    const int wr   = wave >> 2;   // 0..1 -> M half (128 rows)
    const int wc   = wave & 3;    // 0..3 -> N quarter (64 cols)

    // XCD-bijective swizzle: nwg=896 (16x56), 896%8==0
    const int bid = blockIdx.x;
    const int cpx = (M_DIM / BM) * (N_DIM / BN) / 8;   // 112
    const int wg  = (bid & 7) * cpx + (bid >> 3);
    const int tiles_n = N_DIM / BN;                    // 56
    const int tm = wg / tiles_n, tn = wg % tiles_n;
    const int m0 = tm * BM, n0 = tn * BN;

    // --- staging (verbatim round 4, measured 0 conflicts) ---
    const int srow = t >> 2;
    const int scb  = ((t & 3) * 16) ^ (((t >> 3) & 3) << 4);
    const char* aS = (const char*)A + (size_t)(m0 + srow) * K_DIM * 2 + scb;
    const char* bS = (const char*)B + (size_t)(n0 + srow) * K_DIM * 2 + scb;
    const size_t sweepG = (size_t)128 * K_DIM * 2;
    char* sbase = smem;

    auto STAGE_A = [&](int kt) {
        char* d = sbase + (kt & 3) * BUF_BYTES + t * 16;
        const char* s = aS + (size_t)kt * 64;
        GLOAD16(s, d);
        GLOAD16(s + sweepG, d + 8192);
    };
    auto STAGE_B = [&](int kt) {
        char* d = sbase + (kt & 3) * BUF_BYTES + 16384 + t * 16;
        const char* s = bS + (size_t)kt * 64;
        GLOAD16(s, d);
        GLOAD16(s + sweepG, d + 8192);
    };

    // --- ds_read addressing (verbatim round 4) ---
    const int lane15 = lane & 15;
    const int pkb = ((lane >> 4) * 16) ^ (((lane >> 1) & 3) << 4);
    const int aRowB = (wr * 128 + lane15) * 64 + pkb;          // + mi*1024
    const int bRowB = (wc * 64 + lane15) * 64 + pkb + 16384;   // + ni*1024

    f32x4 acc[8][4] = {};
    bf16x8 afc[4], bfc[4];   // "cur" c0 set (af m0-3 + bf)
    bf16x8 afn[4], bfn[4];   // "next" c0 set
    bf16x8 af1[4];           // c1 set (af m4-7), reused every tile

    #define LA4(BUF, AF, BASE) do { _Pragma("unroll") \
        for (int i_ = 0; i_ < 4; ++i_) \
            AF[i_] = *(const bf16x8*)((BUF) + aRowB + ((BASE) + i_) * 1024); \
        } while (0)
    #define LB4(BUF, BF) do { _Pragma("unroll") \
        for (int n_ = 0; n_ < 4; ++n_) \
            BF[n_] = *(const bf16x8*)((BUF) + bRowB + n_ * 1024); \
        } while (0)
    #define MM16(AF, BF, AB) do { _Pragma("unroll") \
        for (int mi_ = 0; mi_ < 4; ++mi_) { _Pragma("unroll") \
            for (int ni_ = 0; ni_ < 4; ++ni_) \
                acc[(AB) + mi_][ni_] = __builtin_amdgcn_mfma_f32_16x16x32_bf16( \
                    AF[mi_], BF[ni_], acc[(AB) + mi_][ni_], 0, 0, 0); } \
        } while (0)

    // --- prologue: stage tiles 0,1,2; publish tiles 0 AND 1 (retire 8,
    // leave tile2's 4). Then issue tile0's c0 reads.
    STAGE_A(0); STAGE_B(0);
    STAGE_A(1); STAGE_B(1);
    STAGE_A(2); STAGE_B(2);
    WAITVM(4);
    __builtin_amdgcn_s_barrier();
    SB0();
    LA4(sbase, afc, 0);
    LB4(sbase, bfc);

    for (int it = 0; it < NT / 2; ++it) {
        // ================= even kt: cur = afc/bfc, next = afn/bfn =========
        {
            const int kt = 2 * it;
            const char* buf = sbase + (kt & 3) * BUF_BYTES;
            LA4(buf, af1, 4);                         // c1: 4 reads
            if (kt + 3 < NT) { STAGE_A(kt + 3); STAGE_B(kt + 3); }
            WAITLGKM(4);                              // c0(kt) done
            SB0();
            __builtin_amdgcn_s_setprio(1);
            MM16(afc, bfc, 0);                        // 16 MFMA; c1 in flight
            __builtin_amdgcn_s_setprio(0);
            {   // c0(kt+1): kt+1 <= 127 always for even kt
                const char* nb = sbase + ((kt + 1) & 3) * BUF_BYTES;
                LA4(nb, afn, 0);
                LB4(nb, bfn);                         // 8 reads
            }
            WAITLGKM(8);                              // c1(kt) done
            SB0();
            __builtin_amdgcn_s_setprio(1);
            MM16(af1, bfc, 4);                        // 16 MFMA; c0(kt+1) flows
            __builtin_amdgcn_s_setprio(0);
            if (kt + 3 < NT) WAITVM(4); else WAITVM(0);
            __builtin_amdgcn_s_barrier();
            SB0();
        }
        // ================= odd kt: cur = afn/bfn, next = afc/bfc ==========
        {
            const int kt = 2 * it + 1;
            const char* buf = sbase + (kt & 3) * BUF_BYTES;
            LA4(buf, af1, 4);
            if (kt + 3 < NT) { STAGE_A(kt + 3); STAGE_B(kt + 3); }
            WAITLGKM(4);                              // c0(kt) done
            SB0();
            __builtin_amdgcn_s_setprio(1);
            MM16(afn, bfn, 0);
            __builtin_amdgcn_s_setprio(0);
            if (kt + 1 < NT) {
                const char* nb = sbase + ((kt + 1) & 3) * BUF_BYTES;
                LA4(nb, afc, 0);
                LB4(nb, bfc);
                WAITLGKM(8);                          // c1(kt) done
            } else {
                WAITLGKM(0);                          // last tile: drain c1
            }
            SB0();
            __builtin_amdgcn_s_setprio(1);
            MM16(af1, bfn, 4);
            __builtin_amdgcn_s_setprio(0);
            if (kt + 3 < NT) WAITVM(4); else WAITVM(0);
            __builtin_amdgcn_s_barrier();
            SB0();
        }
    }

    #undef LA4
    #undef LB4
    #undef MM16

    // ---- epilogue: y = acc*qxscale[m] + bias[n]; silu ----
    // D layout: col = lane&15 (n), row = (lane>>4)*4 + reg (m)
    const int c_col = lane & 15;
    const int c_r4  = (lane >> 4) * 4;
    #pragma unroll
    for (int mi = 0; mi < 8; ++mi) {
        const int mg = m0 + wr * 128 + mi * 16 + c_r4;
        float qs[4];
        #pragma unroll
        for (int r = 0; r < 4; ++r) qs[r] = qxscale[mg + r];
        #pragma unroll
        for (int ni = 0; ni < 4; ++ni) {
            const int ng = n0 + wc * 64 + ni * 16 + c_col;
            const float bv = bias[ng];
            #pragma unroll
            for (int r = 0; r < 4; ++r) {
                const float y = acc[mi][ni][r] * qs[r] + bv;
                out[(size_t)(mg + r) * N_DIM + ng] = y / (1.f + __expf(-y));
            }
        }
    }
}

// ---------------- fallback: round-1 fused kernel ----------------

constexpr int FBM = 128, FBN = 128, FBK = 64;
constexpr int FLDA = 72;

__global__ __launch_bounds__(256) void gateproj_fused_kernel(
    const float* __restrict__ qx, const float* __restrict__ qxscale,
    const int* __restrict__ wq, const float* __restrict__ wscale,
    const float* __restrict__ bias, float* __restrict__ out)
{
    __shared__ __bf16 sA[FBM * FLDA];
    __shared__ __bf16 sB[FBN * FLDA];

    const int tid  = threadIdx.x;
    const int lane = tid & 63;
    const int wave = tid >> 6;
    const int wm = wave >> 1, wn = wave & 1;

    const int bid = blockIdx.x;
    const int cpx = (M_DIM / FBM) * (N_DIM / FBN) / 8;
    const int wg  = (bid & 7) * cpx + (bid >> 3);
    const int tiles_n = N_DIM / FBN;
    const int tm = wg / tiles_n, tn = wg % tiles_n;
    const int m0 = tm * FBM, n0 = tn * FBN;

    const int a_row = tid >> 4;
    const int a_col = (tid & 15) * 4;
    const float* aPtr = qx + (size_t)(m0 + a_row) * K_DIM + a_col;

    const int b_row = tid >> 1;
    const int b_wb  = (tid & 1) * 4;
    const int*   bPtr = wq     + (size_t)(n0 + b_row) * (K_DIM / 8) + b_wb;
    const float* sPtr = wscale + (size_t)(n0 + b_row) * (K_DIM / GSZ);

    float4 aReg[8];
    int    bRegW[4];
    float  bScl;
    f32x4 acc[4][4] = {};

    auto LOAD = [&](int kt) {
        const float* ap = aPtr + kt * FBK;
        #pragma unroll
        for (int i = 0; i < 8; ++i)
            aReg[i] = *(const float4*)(ap + (size_t)i * 16 * K_DIM);
        int4 b = *(const int4*)(bPtr + kt * 8);
        bRegW[0] = b.x; bRegW[1] = b.y; bRegW[2] = b.z; bRegW[3] = b.w;
        bScl = sPtr[kt >> 1];
    };

    auto STORE = [&]() {
        #pragma unroll
        for (int i = 0; i < 8; ++i) {
            bf16x4 v;
            v[0] = (__bf16)aReg[i].x; v[1] = (__bf16)aReg[i].y;
            v[2] = (__bf16)aReg[i].z; v[3] = (__bf16)aReg[i].w;
            *(bf16x4*)&sA[(a_row + i * 16) * FLDA + a_col] = v;
        }
        const int cb = (tid & 1) * 32;
        #pragma unroll
        for (int wi = 0; wi < 4; ++wi) {
            const int w = bRegW[wi];
            bf16x8 o;
            #pragma unroll
            for (int j = 0; j < 8; ++j) {
                const int v = ((int)((unsigned)w << (28 - 4 * j))) >> 28;
                o[j] = (__bf16)((float)v * bScl);
            }
            *(bf16x8*)&sB[b_row * FLDA + cb + wi * 8] = o;
        }
    };

    LOAD(0); STORE(); __syncthreads();

    const int FNT = K_DIM / FBK;
    for (int kt = 0; kt < FNT; ++kt) {
        if (kt + 1 < FNT) LOAD(kt + 1);
        #pragma unroll
        for (int kk = 0; kk < 2; ++kk) {
            bf16x8 af2[4], bfr2[4];
            const int ko = kk * 32 + (lane >> 4) * 8;
            #pragma unroll
            for (int mi = 0; mi < 4; ++mi)
                af2[mi] = *(const bf16x8*)&sA[(wm * 64 + mi * 16 + (lane & 15)) * FLDA + ko];
            #pragma unroll
            for (int ni = 0; ni < 4; ++ni)
                bfr2[ni] = *(const bf16x8*)&sB[(wn * 64 + ni * 16 + (lane & 15)) * FLDA + ko];
            #pragma unroll
            for (int mi = 0; mi < 4; ++mi)
                #pragma unroll
                for (int ni = 0; ni < 4; ++ni)
                    acc[mi][ni] = __builtin_amdgcn_mfma_f32_16x16x32_bf16(
                        af2[mi], bfr2[ni], acc[mi][ni], 0, 0, 0);
        }
        __syncthreads();
        if (kt + 1 < FNT) { STORE(); __syncthreads(); }
    }

    const int c_col = lane & 15;
    const int c_r4  = (lane >> 4) * 4;
    #pragma unroll
    for (int mi = 0; mi < 4; ++mi) {
        const int mg = m0 + wm * 64 + mi * 16 + c_r4;
        float qs[4];
        #pragma unroll
        for (int r = 0; r < 4; ++r) qs[r] = qxscale[mg + r];
        #pragma unroll
        for (int ni = 0; ni < 4; ++ni) {
            const int ng = n0 + wn * 64 + ni * 16 + c_col;
            const float bv = bias[ng];
            #pragma unroll
            for (int r = 0; r < 4; ++r) {
                const float y = acc[mi][ni][r] * qs[r] + bv;
                out[(size_t)(mg + r) * N_DIM + ng] = y / (1.f + __expf(-y));
            }
        }
    }
}

// ---------------- launch ----------------

extern "C" void kernel_launch(void* const* d_in, const int* in_sizes, int n_in,
                              void* d_out, int out_size, void* d_ws, size_t ws_size,
                              hipStream_t stream) {
    const float* qx      = (const float*)d_in[0];
    const float* qxscale = (const float*)d_in[1];
    const int*   wq      = (const int*)d_in[2];
    const float* wscale  = (const float*)d_in[3];
    const float* bias    = (const float*)d_in[4];
    float* out = (float*)d_out;

    const size_t needA = (size_t)M_DIM * K_DIM * 2;
    const size_t needW = (size_t)N_DIM * K_DIM * 2;

    if (ws_size >= needA + needW) {
        __bf16* Abf = (__bf16*)d_ws;
        __bf16* Wbf = Abf + (size_t)M_DIM * K_DIM;

        hipLaunchKernelGGL(convertA_kernel, dim3(M_DIM * K_DIM / 8 / 256), dim3(256),
                           0, stream, qx, Abf);
        hipLaunchKernelGGL(dequantW_kernel, dim3(N_DIM * (K_DIM / 8) / 256), dim3(256),
                           0, stream, wq, wscale, Wbf);

        const int grid = (M_DIM / BM) * (N_DIM / BN);   // 896
        hipLaunchKernelGGL(gemm256_kernel, dim3(grid), dim3(512), 0, stream,
                           Abf, Wbf, qxscale, bias, out);
    } else {
        const int grid = (M_DIM / FBM) * (N_DIM / FBN);
        hipLaunchKernelGGL(gateproj_fused_kernel, dim3(grid), dim3(256), 0, stream,
                           qx, qxscale, wq, wscale, bias, out);
    }
}